// Round 7
// baseline (2525.244 us; speedup 1.0000x reference)
//
#include <hip/hip_runtime.h>
#include <stdint.h>

// CharRNN MI355X — persistent-RNN, C=64 K-split edition.
//   K1 k_prep  : proj[v][h] = embedding[v,:] @ W_ih + b_h  (VOCAB=64 table)
//   K1b k_prep2: W_ho -> bf16 MFMA-B fragment order in global (L2-streamed)
//   K2 k_rnn   : persistent 256 blocks (1/CU), 16 groups x 16 blocks.
//                Block (gi,gj): rows gi*16..+16, cols gj*64..+64.
//                W_hh slice bf16 frag-order in LDS (128KB). Per step: wave w
//                coherent-loads A-frags for K in [w*256,(w+1)*256) ONLY
//                (8KB/wave, zero redundancy), MFMAs partials for all 4
//                n-tiles, 16KB LDS cross-wave reduce, tanh, coherent store,
//                drain, per-block flag publish, lane-parallel 16-flag poll.
//                Every 16 steps: logits for tsel=t-15+gj (A from ring, B
//                from frag-order W_ho via L2) -> d_out.
// d_ws: proj f32 @0 (256KB) | whof @256K (128KB) | flags @384K (32KB) |
//       ring bf16 @1MB (16MB).   Total need 17MB.

#define BATCH 256
#define SEQ   512
#define HID   1024
#define VOC   64
#define EMB   256
#define FINAL_OFF (BATCH * SEQ * VOC)   // 8388608
#define NSLOT 32

typedef __attribute__((ext_vector_type(8))) short short8;
typedef __attribute__((ext_vector_type(4))) float f32x4;
typedef unsigned long long u64;

__device__ inline unsigned short f2bf(float f) {
  union { float f; unsigned u; } v; v.f = f;
  unsigned u = v.u;
  return (unsigned short)((u + 0x7FFFu + ((u >> 16) & 1u)) >> 16);  // RNE
}
__device__ inline float bf2f(unsigned short b) {
  union { unsigned u; float f; } v; v.u = ((unsigned)b) << 16; return v.f;
}
__device__ inline u64 cload64(const void* p) {
  return __hip_atomic_load((const u64*)p, __ATOMIC_RELAXED,
                           __HIP_MEMORY_SCOPE_AGENT);
}
__device__ inline unsigned cload32(const void* p) {
  return __hip_atomic_load((const unsigned*)p, __ATOMIC_RELAXED,
                           __HIP_MEMORY_SCOPE_AGENT);
}
__device__ inline void cstore32(void* p, unsigned v) {
  __hip_atomic_store((unsigned*)p, v, __ATOMIC_RELAXED,
                     __HIP_MEMORY_SCOPE_AGENT);
}
__device__ inline short8 comb(u64 lo, u64 hi) {
  union { u64 d[2]; short8 s; } c; c.d[0] = lo; c.d[1] = hi; return c.s;
}

// Wait until all 16 blocks of group gi have published step t (flag >= t+1).
// Each block's flag word sits in its own 128B line; lanes poll in parallel.
__device__ inline void poll_group(const unsigned* flags, int gi, int t, int lane) {
  const unsigned* fp =
      flags + (size_t)(gi * 16 + (lane & 15)) * 32 + (t & (NSLOT - 1));
  unsigned target = (unsigned)(t + 1);
  int guard = 0;
  for (;;) {
    unsigned f = cload32(fp);
    if (__ballot(f >= target) == ~0ull) break;
    __builtin_amdgcn_s_sleep(1);
    if (++guard > (1 << 15)) break;      // bailout: wrong answer beats a hang
  }
}

// ---------------- K1: projection table -------------------------------------
__global__ __launch_bounds__(256) void k_prep(const float* __restrict__ emb,
                                              const float* __restrict__ Wih,
                                              const float* __restrict__ bh,
                                              float* __restrict__ proj) {
  __shared__ float es[EMB];
  const int v = blockIdx.x >> 2;
  const int p = blockIdx.x & 3;
  const int tid = threadIdx.x;
  es[tid] = emb[v * EMB + tid];
  __syncthreads();
  const int h = p * 256 + tid;
  float acc = bh[h];
  for (int e = 0; e < EMB; ++e) acc += es[e] * Wih[e * HID + h];
  proj[v * HID + h] = acc;
}

// ---------------- K1b: W_ho -> fragment order ------------------------------
// whof[((kb*4+q)*64 + v)*8 + j] = bf16(Who[(kb*32+q*8+j)*VOC + v])
__global__ __launch_bounds__(256) void k_prep2(const float* __restrict__ Who,
                                               unsigned short* __restrict__ whof) {
  int u = blockIdx.x * 256 + threadIdx.x;          // 65536 total
  int j = u & 7, v = (u >> 3) & 63, q = (u >> 9) & 3, kb = u >> 11;
  whof[u] = f2bf(Who[(kb * 32 + q * 8 + j) * VOC + v]);
}

// ---------------- K2: persistent recurrence + inline logits ----------------
// LDS: w_lds 131072 | red 16384 | p_lds 8192 | xs 64  => 155712
__global__ __launch_bounds__(256, 1) void k_rnn(
    const int* __restrict__ x, const float* __restrict__ Whh,
    const float* __restrict__ proj, const unsigned short* __restrict__ whof,
    const float* __restrict__ bo, unsigned short* __restrict__ ring,
    unsigned* __restrict__ flags, float* __restrict__ out,
    float* __restrict__ final_out) {
  extern __shared__ char smem[];
  unsigned short* w_lds = (unsigned short*)smem;             // 131072
  float*          red   = (float*)(smem + 131072);           // 16384
  unsigned short* p_lds = (unsigned short*)(smem + 147456);  // 8192
  int*            xs    = (int*)(smem + 155648);             // 64

  const int tid = threadIdx.x, bid = blockIdx.x;
  // XCD swizzle: all 16 blocks of a group share bid%8 (round-robin heuristic;
  // correctness does not depend on it — all exchange is coherent).
  const int gi = ((bid & 7) << 1) | ((bid >> 3) & 1);        // 0..15
  const int gj = bid >> 4;                                   // 0..15
  const int row0 = gi * 16, colb = gj * 64;
  const int w = tid >> 6, lane = tid & 63;
  const int l15 = lane & 15, q = lane >> 4;

  // W_hh column slice -> LDS bf16 frag order [kb][q][n][j]  (once)
  for (int it = 0; it < 256; ++it) {
    int u = it * 256 + tid;
    int j = u & 7, n = (u >> 3) & 63, qq = (u >> 9) & 3, kb = u >> 11;
    w_lds[u] = f2bf(Whh[(kb * 32 + qq * 8 + j) * HID + colb + n]);
  }
  // proj slice [64 voc][64 local cols] -> LDS bf16          (once)
  for (int it = 0; it < 16; ++it) {
    int u = it * 256 + tid;
    p_lds[u] = f2bf(proj[(u >> 6) * HID + colb + (u & 63)]);
  }
  __syncthreads();

  const float biasv = bo[w * 16 + l15];
  unsigned* myflag = flags + (size_t)(gi * 16 + gj) * 32;

  for (int t = 0; t < SEQ; ++t) {
    if (tid < 16) xs[tid] = x[(row0 + tid) * SEQ + t];       // L2, overlapped
    f32x4 a0 = {0.f,0.f,0.f,0.f}, a1 = {0.f,0.f,0.f,0.f};
    f32x4 a2 = {0.f,0.f,0.f,0.f}, a3 = {0.f,0.f,0.f,0.f};
    if (t > 0) {
      // 1) wait for group's h_{t-1}, then stream this wave's K-range A-frags
      poll_group(flags, gi, t - 1, lane);
      const unsigned short* sp =
          ring + (size_t)((t - 1) & (NSLOT - 1)) * (BATCH * HID) +
          (size_t)(row0 + l15) * HID + w * 256 + q * 8;
      u64 alo[8], ahi[8];
      #pragma unroll
      for (int kk = 0; kk < 8; ++kk) {
        alo[kk] = cload64(sp + kk * 32);
        ahi[kk] = cload64(sp + kk * 32 + 4);
      }
      #pragma unroll
      for (int kk = 0; kk < 8; ++kk) {
        short8 af = comb(alo[kk], ahi[kk]);
        int kb = w * 8 + kk;
        const unsigned short* bb = w_lds + (size_t)((kb * 4 + q) * 64) * 8;
        a0 = __builtin_amdgcn_mfma_f32_16x16x32_bf16(af, *(const short8*)(bb + l15 * 8),          a0, 0, 0, 0);
        a1 = __builtin_amdgcn_mfma_f32_16x16x32_bf16(af, *(const short8*)(bb + (16 + l15) * 8),   a1, 0, 0, 0);
        a2 = __builtin_amdgcn_mfma_f32_16x16x32_bf16(af, *(const short8*)(bb + (32 + l15) * 8),   a2, 0, 0, 0);
        a3 = __builtin_amdgcn_mfma_f32_16x16x32_bf16(af, *(const short8*)(bb + (48 + l15) * 8),   a3, 0, 0, 0);
      }
      // 2) publish partials for the 3 n-tiles this wave does not own
      if (w != 0) *(f32x4*)(red + ((w * 4 + 0) * 64 + lane) * 4) = a0;
      if (w != 1) *(f32x4*)(red + ((w * 4 + 1) * 64 + lane) * 4) = a1;
      if (w != 2) *(f32x4*)(red + ((w * 4 + 2) * 64 + lane) * 4) = a2;
      if (w != 3) *(f32x4*)(red + ((w * 4 + 3) * 64 + lane) * 4) = a3;
    }
    __syncthreads();                       // reduce visibility (+ xs at t==0)
    f32x4 own = (w == 0) ? a0 : (w == 1) ? a1 : (w == 2) ? a2 : a3;
    if (t > 0) {
      #pragma unroll
      for (int w2 = 0; w2 < 4; ++w2) {
        if (w2 != w) {
          f32x4 p = *(const f32x4*)(red + ((w2 * 4 + w) * 64 + lane) * 4);
          own[0] += p[0]; own[1] += p[1]; own[2] += p[2]; own[3] += p[3];
        }
      }
    }
    // 3) epilogue: wave w owns n-tile w: rows q*4+r, col w*16+l15
    unsigned short* st = ring + (size_t)(t & (NSLOT - 1)) * (BATCH * HID);
    const int colg = colb + w * 16 + l15;
    float hv[4];
    #pragma unroll
    for (int r = 0; r < 4; ++r) {
      float pre = bf2f(p_lds[xs[q * 4 + r] * 64 + w * 16 + l15]) + own[r];
      hv[r] = tanhf(pre);
      if (t == SEQ - 1) final_out[(row0 + q * 4 + r) * HID + colg] = hv[r];
    }
    #pragma unroll
    for (int r = 0; r < 4; ++r) {
      unsigned m = f2bf(hv[r]);
      unsigned o = (unsigned)__shfl_xor((int)m, 1);
      if (!(l15 & 1))
        cstore32(st + (size_t)(row0 + q * 4 + r) * HID + colg, m | (o << 16));
    }
    // 4) drain stores + guard red/xs reuse, publish flag
    __syncthreads();                       // vmcnt(0) drain = release
    if (tid == 0) cstore32(myflag + (t & (NSLOT - 1)), (unsigned)(t + 1));
    // 5) logits every 16 steps: group rows x tsel=t-15+gj x all 64 voc
    if ((t & 15) == 15) {
      int tsel = t - 15 + gj;              // <= t
      poll_group(flags, gi, tsel, lane);   // monotone; usually satisfied
      const unsigned short* ap =
          ring + (size_t)(tsel & (NSLOT - 1)) * (BATCH * HID) +
          (size_t)(row0 + l15) * HID + q * 8;
      f32x4 lc = {0.f,0.f,0.f,0.f};
      for (int c = 0; c < 4; ++c) {
        u64 alo[8], ahi[8];
        #pragma unroll
        for (int kk = 0; kk < 8; ++kk) {
          alo[kk] = cload64(ap + (c * 8 + kk) * 32);
          ahi[kk] = cload64(ap + (c * 8 + kk) * 32 + 4);
        }
        #pragma unroll
        for (int kk = 0; kk < 8; ++kk) {
          int kb = c * 8 + kk;
          short8 bf = *(const short8*)(whof + (size_t)((kb * 4 + q) * 64 + w * 16 + l15) * 8);
          lc = __builtin_amdgcn_mfma_f32_16x16x32_bf16(comb(alo[kk], ahi[kk]), bf, lc, 0, 0, 0);
        }
      }
      #pragma unroll
      for (int r = 0; r < 4; ++r)
        out[((size_t)(row0 + q * 4 + r) * SEQ + tsel) * VOC + w * 16 + l15] =
            lc[r] + biasv;
    }
  }
}

// ---------------- launch ----------------------------------------------------
extern "C" void kernel_launch(void* const* d_in, const int* in_sizes, int n_in,
                              void* d_out, int out_size, void* d_ws, size_t ws_size,
                              hipStream_t stream) {
  const int*   x   = (const int*)d_in[0];
  const float* emb = (const float*)d_in[1];
  const float* Wih = (const float*)d_in[2];
  const float* Whh = (const float*)d_in[3];
  const float* bh  = (const float*)d_in[4];
  const float* Who = (const float*)d_in[5];
  const float* bo  = (const float*)d_in[6];
  float* out = (float*)d_out;

  char* ws = (char*)d_ws;
  float*          proj  = (float*)ws;                         // 262144 B
  unsigned short* whof  = (unsigned short*)(ws + 262144);     // 131072 B
  unsigned*       flags = (unsigned*)(ws + 393216);           // 32768 B
  unsigned short* ring  = (unsigned short*)(ws + (1 << 20));  // 16 MiB

  size_t need = (size_t)(1 << 20) + (size_t)NSLOT * BATCH * HID * 2;
  if (ws_size < need) return;  // diagnostic fail instead of a fault

  (void)hipFuncSetAttribute(reinterpret_cast<const void*>(k_rnn),
                            hipFuncAttributeMaxDynamicSharedMemorySize, 155712);

  k_prep<<<256, 256, 0, stream>>>(emb, Wih, bh, proj);
  k_prep2<<<256, 256, 0, stream>>>(Who, whof);
  hipMemsetAsync(flags, 0, 32768, stream);
  k_rnn<<<256, 256, 155712, stream>>>(x, Whh, proj, whof, bo, ring, flags,
                                      out, out + FINAL_OFF);
}